// Round 2
// baseline (109322.876 us; speedup 1.0000x reference)
//
#include <hip/hip_runtime.h>
#include <math.h>

#define BB 64
#define TT 2048
#define RR 256
#define BLK 24   // far-tap block (min far delay)

// One WG per batch. 1024 threads = 4 row-groups (q) x 256 columns (s).
// Tap structure: d=1 -> W0 in VGPRs (pre-scaled), every step.
//                d=4 -> W1 streamed once per 4-step sub-block (ring hwin in LDS).
//                d=24,96,168 -> GEMM once per 24-step block into Gl (LDS).
__global__ __launch_bounds__(1024)
void reservoir_kernel(const float* __restrict__ x,
                      const float* __restrict__ W_in,
                      const float* __restrict__ W_fb,
                      const float* __restrict__ tapw,
                      const float* __restrict__ bias,
                      float* __restrict__ out)
{
    const int b   = blockIdx.x;
    const int tid = threadIdx.x;
    const int q   = tid >> 8;    // row group: rows 64q..64q+63
    const int s   = tid & 255;   // output column

    __shared__ float xs[TT];               // 8 KB
    __shared__ float hwin[8][RR];          // 4 KB ring of recent h (slots t&7)
    __shared__ float hb3[3][BLK][RR];      // 73.7 KB staged far history (pre-scaled by tw)
    __shared__ float part4[4][4][RR];      // 16 KB cross-q reduction buffer
    __shared__ float Gl[BLK][RR];          // 24 KB far-tap contributions for current block

    for (int i = tid; i < TT; i += 1024) xs[i] = x[b * TT + i];
    for (int i = tid; i < 8 * RR; i += 1024) ((float*)hwin)[i] = 0.0f;

    // softmax(tap_weights), redundant per thread
    float w0 = tapw[0], w1 = tapw[1], w2 = tapw[2], w3 = tapw[3], w4 = tapw[4];
    float mxv = fmaxf(fmaxf(fmaxf(w0, w1), fmaxf(w2, w3)), w4);
    float e0 = expf(w0 - mxv), e1 = expf(w1 - mxv), e2 = expf(w2 - mxv),
          e3 = expf(w3 - mxv), e4 = expf(w4 - mxv);
    float inv = 1.0f / (e0 + e1 + e2 + e3 + e4);
    const float tw0 = e0 * inv, tw1 = e1 * inv;
    const float twf0 = e2 * inv, twf1 = e3 * inv, twf2 = e4 * inv;

    // W0 (tap d=1) in registers, pre-scaled: rows 64q..64q+63, column s.
    float4 w0v[16];
    {
        const float* W0 = W_fb + (64 * q) * RR + s;
#pragma unroll
        for (int i = 0; i < 16; ++i) {
            w0v[i].x = tw0 * W0[(4 * i + 0) * RR];
            w0v[i].y = tw0 * W0[(4 * i + 1) * RR];
            w0v[i].z = tw0 * W0[(4 * i + 2) * RR];
            w0v[i].w = tw0 * W0[(4 * i + 3) * RR];
        }
    }
    const float win_s  = W_in[s];
    const float bias_s = bias[s];
    const float* W1    = W_fb + 1 * RR * RR + (64 * q) * RR + s;  // tap d=4
    const float* outb  = out + (size_t)b * TT * RR;
    float*       outw  = out + (size_t)b * TT * RR;

    float hprev = 0.0f;
    __syncthreads();

    for (int t0 = 0; t0 < TT; t0 += BLK) {
        const int jmax = (TT - t0 < BLK) ? (TT - t0) : BLK;  // 24, tail 8 (mult of 4)

        // ---- stage far-tap history into LDS, pre-scaled by tap weight ----
        for (int i = tid; i < 3 * BLK * RR; i += 1024) {
            int k   = i / (BLK * RR);
            int rem = i - k * (BLK * RR);
            int j   = rem >> 8;
            int r   = rem & 255;
            int dk  = (k == 0) ? 24 : ((k == 1) ? 96 : 168);
            float tk = (k == 0) ? twf0 : ((k == 1) ? twf1 : twf2);
            int tt  = t0 + j - dk;
            hb3[k][j][r] = (tt >= 0) ? tk * outb[tt * RR + r] : 0.0f;
        }
        __syncthreads();

        // ---- far-tap GEMM: Gl[j][s], two chunks of 12 j's (12x W reuse) ----
        for (int c = 0; c < 2; ++c) {
            float acc[12];
#pragma unroll
            for (int u = 0; u < 12; ++u) acc[u] = 0.0f;
#pragma unroll
            for (int k = 0; k < 3; ++k) {
                const float* Wk = W_fb + (2 + k) * RR * RR + (64 * q) * RR + s;
#pragma unroll
                for (int rc = 0; rc < 8; ++rc) {   // 8 chunks of 8 rows
                    float wt[8];
#pragma unroll
                    for (int i = 0; i < 8; ++i) wt[i] = Wk[(8 * rc + i) * RR];
#pragma unroll
                    for (int u = 0; u < 12; ++u) {
                        const float4* hp = (const float4*)&hb3[k][12 * c + u][64 * q + 8 * rc];
                        float4 ha = hp[0], hc = hp[1];
                        float a = acc[u];
                        a = fmaf(ha.x, wt[0], a); a = fmaf(ha.y, wt[1], a);
                        a = fmaf(ha.z, wt[2], a); a = fmaf(ha.w, wt[3], a);
                        a = fmaf(hc.x, wt[4], a); a = fmaf(hc.y, wt[5], a);
                        a = fmaf(hc.z, wt[6], a); a = fmaf(hc.w, wt[7], a);
                        acc[u] = a;
                    }
                }
            }
            // cross-q reduce 12 j's in 3 rounds of 4 via part4
            for (int g = 0; g < 3; ++g) {
#pragma unroll
                for (int u = 0; u < 4; ++u) part4[q][u][s] = acc[4 * g + u];
                __syncthreads();
                if (q == 0) {
#pragma unroll
                    for (int u = 0; u < 4; ++u)
                        Gl[12 * c + 4 * g + u][s] = part4[0][u][s] + part4[1][u][s]
                                                  + part4[2][u][s] + part4[3][u][s];
                }
                __syncthreads();
            }
        }

        // ---- sub-blocks of 4 steps ----
        for (int t4 = t0; t4 < t0 + jmax; t4 += 4) {
            // tap d=4 GEMM: operands h_{t4-4..t4-1} from hwin ring (slots contiguous)
            float a4[4] = {0.0f, 0.0f, 0.0f, 0.0f};
#pragma unroll
            for (int rc = 0; rc < 4; ++rc) {
                float wt[16];
#pragma unroll
                for (int i = 0; i < 16; ++i) wt[i] = tw1 * W1[(16 * rc + i) * RR];
#pragma unroll
                for (int u = 0; u < 4; ++u) {
                    const float4* hp = (const float4*)&hwin[(t4 - 4 + u) & 7][64 * q + 16 * rc];
                    float4 ha = hp[0], hbv = hp[1], hc = hp[2], hd = hp[3];
                    float a = a4[u];
                    a = fmaf(ha.x, wt[0],  a); a = fmaf(ha.y, wt[1],  a);
                    a = fmaf(ha.z, wt[2],  a); a = fmaf(ha.w, wt[3],  a);
                    a = fmaf(hbv.x, wt[4], a); a = fmaf(hbv.y, wt[5], a);
                    a = fmaf(hbv.z, wt[6], a); a = fmaf(hbv.w, wt[7], a);
                    a = fmaf(hc.x, wt[8],  a); a = fmaf(hc.y, wt[9],  a);
                    a = fmaf(hc.z, wt[10], a); a = fmaf(hc.w, wt[11], a);
                    a = fmaf(hd.x, wt[12], a); a = fmaf(hd.y, wt[13], a);
                    a = fmaf(hd.z, wt[14], a); a = fmaf(hd.w, wt[15], a);
                    a4[u] = a;
                }
            }
#pragma unroll
            for (int u = 0; u < 4; ++u) part4[q][u][s] = a4[u];
            __syncthreads();
            float gcur[4];
#pragma unroll
            for (int u = 0; u < 4; ++u)
                gcur[u] = Gl[t4 - t0 + u][s] + part4[0][u][s] + part4[1][u][s]
                        + part4[2][u][s] + part4[3][u][s];
            __syncthreads();

            // 4 sequential steps: tap d=1 from registers
#pragma unroll
            for (int u = 0; u < 4; ++u) {
                const int t = t4 + u;
                const float4* hp = (const float4*)&hwin[(t - 1) & 7][64 * q];
                float fb0 = 0.0f;
#pragma unroll
                for (int i = 0; i < 16; ++i) {
                    float4 h4 = hp[i];
                    fb0 = fmaf(h4.x, w0v[i].x, fb0);
                    fb0 = fmaf(h4.y, w0v[i].y, fb0);
                    fb0 = fmaf(h4.z, w0v[i].z, fb0);
                    fb0 = fmaf(h4.w, w0v[i].w, fb0);
                }
                part4[q][0][s] = fb0;
                __syncthreads();
                float fb = part4[0][0][s] + part4[1][0][s] + part4[2][0][s] + part4[3][0][s];
                float h  = 0.9f * hprev + 0.1f * tanhf(xs[t] * win_s + fb + gcur[u] + bias_s);
                hprev = h;
                if (q == 0) {
                    hwin[t & 7][s]   = h;
                    outw[t * RR + s] = h;
                }
                __syncthreads();
            }
        }
    }
}

extern "C" void kernel_launch(void* const* d_in, const int* in_sizes, int n_in,
                              void* d_out, int out_size, void* d_ws, size_t ws_size,
                              hipStream_t stream) {
    const float* x    = (const float*)d_in[0];   // (64, 2048, 1)
    const float* W_in = (const float*)d_in[1];   // (256, 1)
    const float* W_fb = (const float*)d_in[2];   // (5, 256, 256)
    const float* tapw = (const float*)d_in[3];   // (5,)
    const float* bias = (const float*)d_in[4];   // (256,)
    float* out = (float*)d_out;                  // (64, 2048, 256)

    reservoir_kernel<<<BB, 1024, 0, stream>>>(x, W_in, W_fb, tapw, bias, out);
}

// Round 3
// 7625.323 us; speedup vs baseline: 14.3368x; 14.3368x over previous
//
#include <hip/hip_runtime.h>
#include <math.h>

#define BB 64
#define TT 2048
#define RR 256
#define BLK 24
#define NTHR 512

// One WG per batch. 512 threads = 8 waves.
// Wave w: shalf = w&1 (lane covers s0 = 128*shalf+lane, s1 = s0+64), rg = w>>1.
// tap d=1:  W0 pre-scaled in VGPRs (128/thread), h via LDS float4 broadcast.
// tap d=4:  GEMM per 4-step sub-block, W1 streamed coalesced from L1/L2 (read once/CU).
// taps 24/96/168: fused 24x256x768 GEMM per 24-step block, h staged+scaled in LDS,
//                 broadcast reads; W streamed coalesced, reused across 12 j in regs.
__global__ __launch_bounds__(NTHR, 2)
void reservoir_kernel(const float* __restrict__ x,
                      const float* __restrict__ W_in,
                      const float* __restrict__ W_fb,
                      const float* __restrict__ tapw,
                      const float* __restrict__ bias,
                      float* __restrict__ out)
{
    const int b     = blockIdx.x;
    const int tid   = threadIdx.x;
    const int lane  = tid & 63;
    const int w     = tid >> 6;     // wave 0..7
    const int shalf = w & 1;
    const int rg    = w >> 1;       // 0..3
    const int s0    = 128 * shalf + lane;
    const int s1    = s0 + 64;

    __shared__ float xs[TT];              // 8 KB
    __shared__ float hwin[8][RR];         // 8 KB ring of recent h, slot t&7
    __shared__ float hbc[BLK][3 * RR];    // 72 KB staged far history (pre-scaled)
    __shared__ float Gl[BLK][RR];         // 24 KB far-tap results for current block
    __shared__ float part[4][6][RR];      // 24 KB cross-wave partials

    for (int i = tid; i < TT; i += NTHR) xs[i] = x[b * TT + i];
    for (int i = tid; i < 8 * RR; i += NTHR) ((float*)hwin)[i] = 0.0f;

    // softmax(tap_weights), redundant per thread
    float tw[5];
    {
        float v0 = tapw[0], v1 = tapw[1], v2 = tapw[2], v3 = tapw[3], v4 = tapw[4];
        float mx = fmaxf(fmaxf(fmaxf(v0, v1), fmaxf(v2, v3)), v4);
        float e0 = expf(v0 - mx), e1 = expf(v1 - mx), e2 = expf(v2 - mx),
              e3 = expf(v3 - mx), e4 = expf(v4 - mx);
        float inv = 1.0f / (e0 + e1 + e2 + e3 + e4);
        tw[0] = e0 * inv; tw[1] = e1 * inv; tw[2] = e2 * inv;
        tw[3] = e3 * inv; tw[4] = e4 * inv;
    }

    // W0 (tap d=1) pre-scaled in VGPRs: rows 64*rg..64*rg+63, cols s0 and s1.
    float4 w0a[16], w0b[16];
    {
        const float* W0 = W_fb;
#pragma unroll
        for (int i = 0; i < 16; ++i) {
            int r = 64 * rg + 4 * i;
            w0a[i].x = tw[0] * W0[(r + 0) * RR + s0];
            w0a[i].y = tw[0] * W0[(r + 1) * RR + s0];
            w0a[i].z = tw[0] * W0[(r + 2) * RR + s0];
            w0a[i].w = tw[0] * W0[(r + 3) * RR + s0];
            w0b[i].x = tw[0] * W0[(r + 0) * RR + s1];
            w0b[i].y = tw[0] * W0[(r + 1) * RR + s1];
            w0b[i].z = tw[0] * W0[(r + 2) * RR + s1];
            w0b[i].w = tw[0] * W0[(r + 3) * RR + s1];
        }
    }

    const float* outb = out + (size_t)b * TT * RR;
    float*       outw = out + (size_t)b * TT * RR;

    // update-phase state (meaningful for tid<256 only; s = tid)
    const float win_s  = W_in[tid & 255];
    const float bias_s = bias[tid & 255];
    float hprev = 0.0f;

    __syncthreads();

    for (int t0 = 0; t0 < TT; t0 += BLK) {
        // ---- stage far-tap history (fused taps d=24,96,168), pre-scaled ----
        // hbc[j][k*256+rr] = tw[2+k] * h[t0+j-dk][rr]  (t0+j-dk <= t0-1 always)
        for (int i = tid; i < BLK * 3 * RR; i += NTHR) {
            int j  = i / (3 * RR);
            int r  = i - j * (3 * RR);
            int k  = r >> 8;
            int rr = r & 255;
            int dkk = (k == 0) ? 24 : ((k == 1) ? 96 : 168);
            float tk = (k == 0) ? tw[2] : ((k == 1) ? tw[3] : tw[4]);
            int tt = t0 + j - dkk;
            hbc[j][r] = (tt >= 0) ? tk * outb[tt * RR + rr] : 0.0f;
        }
        __syncthreads();

        // ---- far GEMM: Gl[j][s] = sum_r hbc[j][r] * Wcat[r][s], 2 passes of 12 j ----
        for (int p = 0; p < 2; ++p) {
            float acc0[12], acc1[12];
#pragma unroll
            for (int j = 0; j < 12; ++j) { acc0[j] = 0.0f; acc1[j] = 0.0f; }

            for (int c = 0; c < 48; ++c) {          // this wave's rows: 192*rg + 4c
                int r  = 192 * rg + 4 * c;
                int k  = r >> 8;
                int rr = r & 255;
                const float* Wb = W_fb + (2 + k) * RR * RR + rr * RR;
                float wa0 = Wb[s0],          wa1 = Wb[s1];
                float wb0 = Wb[RR + s0],     wb1 = Wb[RR + s1];
                float wc0 = Wb[2 * RR + s0], wc1 = Wb[2 * RR + s1];
                float wd0 = Wb[3 * RR + s0], wd1 = Wb[3 * RR + s1];
#pragma unroll
                for (int j = 0; j < 12; ++j) {
                    float4 h4 = *(const float4*)&hbc[12 * p + j][r];  // wave-uniform bcast
                    float a0 = acc0[j], a1 = acc1[j];
                    a0 = fmaf(h4.x, wa0, a0); a0 = fmaf(h4.y, wb0, a0);
                    a0 = fmaf(h4.z, wc0, a0); a0 = fmaf(h4.w, wd0, a0);
                    a1 = fmaf(h4.x, wa1, a1); a1 = fmaf(h4.y, wb1, a1);
                    a1 = fmaf(h4.z, wc1, a1); a1 = fmaf(h4.w, wd1, a1);
                    acc0[j] = a0; acc1[j] = a1;
                }
            }
            // cross-wave (4 r-groups) reduction, 2 rounds of 6 j
            for (int g = 0; g < 2; ++g) {
#pragma unroll
                for (int jr = 0; jr < 6; ++jr) {
                    part[rg][jr][s0] = acc0[6 * g + jr];
                    part[rg][jr][s1] = acc1[6 * g + jr];
                }
                __syncthreads();
#pragma unroll
                for (int m = 0; m < 3; ++m) {
                    int idx = tid + NTHR * m;
                    int jr  = idx >> 8;
                    int s   = idx & 255;
                    Gl[12 * p + 6 * g + jr][s] = part[0][jr][s] + part[1][jr][s]
                                               + part[2][jr][s] + part[3][jr][s];
                }
                __syncthreads();
            }
        }

        // ---- sequential sub-blocks of 4 steps ----
        const int tend = (t0 + BLK < TT) ? (t0 + BLK) : TT;
        for (int t4 = t0; t4 < tend; t4 += 4) {
            // tap d=4 GEMM over this wave's 64 rows, cols s0/s1, 4 steps
            float a40[4] = {0, 0, 0, 0}, a41[4] = {0, 0, 0, 0};
            for (int c = 0; c < 16; ++c) {
                int r = 64 * rg + 4 * c;
                const float* Wb = W_fb + RR * RR + r * RR;
                float w00 = Wb[s0],          w01 = Wb[s1];
                float w10 = Wb[RR + s0],     w11 = Wb[RR + s1];
                float w20 = Wb[2 * RR + s0], w21 = Wb[2 * RR + s1];
                float w30 = Wb[3 * RR + s0], w31 = Wb[3 * RR + s1];
#pragma unroll
                for (int u = 0; u < 4; ++u) {
                    float4 h4 = *(const float4*)&hwin[(t4 - 4 + u) & 7][r];
                    float a0 = a40[u], a1 = a41[u];
                    a0 = fmaf(h4.x, w00, a0); a0 = fmaf(h4.y, w10, a0);
                    a0 = fmaf(h4.z, w20, a0); a0 = fmaf(h4.w, w30, a0);
                    a1 = fmaf(h4.x, w01, a1); a1 = fmaf(h4.y, w11, a1);
                    a1 = fmaf(h4.z, w21, a1); a1 = fmaf(h4.w, w31, a1);
                    a40[u] = a0; a41[u] = a1;
                }
            }
#pragma unroll
            for (int u = 0; u < 4; ++u) {
                part[rg][u][s0] = tw[1] * a40[u];
                part[rg][u][s1] = tw[1] * a41[u];
            }
            __syncthreads();

            // 4 sequential steps
#pragma unroll 1
            for (int u = 0; u < 4; ++u) {
                const int t = t4 + u;
                // tap d=1 partial over this wave's 64 rows
                const float4* hp = (const float4*)&hwin[(t - 1) & 7][64 * rg];
                float f0 = 0.0f, f1 = 0.0f;
#pragma unroll
                for (int i = 0; i < 16; ++i) {
                    float4 h4 = hp[i];   // wave-uniform broadcast
                    f0 = fmaf(h4.x, w0a[i].x, f0); f0 = fmaf(h4.y, w0a[i].y, f0);
                    f0 = fmaf(h4.z, w0a[i].z, f0); f0 = fmaf(h4.w, w0a[i].w, f0);
                    f1 = fmaf(h4.x, w0b[i].x, f1); f1 = fmaf(h4.y, w0b[i].y, f1);
                    f1 = fmaf(h4.z, w0b[i].z, f1); f1 = fmaf(h4.w, w0b[i].w, f1);
                }
                part[rg][4][s0] = f0;
                part[rg][4][s1] = f1;
                __syncthreads();

                if (tid < 256) {
                    const int s = tid;
                    float fb = part[0][4][s] + part[1][4][s] + part[2][4][s] + part[3][4][s]
                             + part[0][u][s] + part[1][u][s] + part[2][u][s] + part[3][u][s]
                             + Gl[t - t0][s];
                    float h = 0.9f * hprev + 0.1f * tanhf(xs[t] * win_s + fb + bias_s);
                    hprev = h;
                    hwin[t & 7][s]   = h;
                    outw[t * RR + s] = h;
                }
                __syncthreads();
            }
        }
    }
}

extern "C" void kernel_launch(void* const* d_in, const int* in_sizes, int n_in,
                              void* d_out, int out_size, void* d_ws, size_t ws_size,
                              hipStream_t stream) {
    const float* x    = (const float*)d_in[0];   // (64, 2048, 1)
    const float* W_in = (const float*)d_in[1];   // (256, 1)
    const float* W_fb = (const float*)d_in[2];   // (5, 256, 256)
    const float* tapw = (const float*)d_in[3];   // (5,)
    const float* bias = (const float*)d_in[4];   // (256,)
    float* out = (float*)d_out;                  // (64, 2048, 256)

    reservoir_kernel<<<BB, NTHR, 0, stream>>>(x, W_in, W_fb, tapw, bias, out);
}

// Round 4
// 3106.037 us; speedup vs baseline: 35.1969x; 2.4550x over previous
//
#include <hip/hip_runtime.h>
#include <math.h>

typedef __attribute__((ext_vector_type(8))) short bf16x8;
typedef __attribute__((ext_vector_type(4))) float f32x4;

#define BB 64
#define TT 2048
#define RR 256
#define BLK 24
#define NTHR 512
#define HB_PAD 776   // 768 + 8: rows 16B-aligned, stride 388 dw = 4 mod 32 -> 2-way (free)
#define HW_PAD 264   // 256 + 8: same properties

__device__ __forceinline__ unsigned short f2bf(float f) {
    unsigned u = __float_as_uint(f);
    return (unsigned short)((u + 0x7FFFu + ((u >> 16) & 1u)) >> 16);  // RNE
}
__device__ __forceinline__ float bf2f(unsigned short h) {
    return __uint_as_float(((unsigned)h) << 16);
}

// ---- Pre-pass: pack tw[tap]*W_fb[tap] into MFMA B-fragment order (bf16) ----
// Layout: chunk c = (tap*8 + kt)*16 + nt; element = c*512 + lane*8 (ushorts).
// Fragment: lane l holds B[k = 32*kt + 8*(l>>4) + j][n = 16*nt + (l&15)], j=0..7.
__global__ void pack_weights(const float* __restrict__ W_fb,
                             const float* __restrict__ tapw,
                             unsigned short* __restrict__ bp) {
    int gid = blockIdx.x * 256 + threadIdx.x;      // 40960 threads
    int l = gid & 63, c = gid >> 6;                // c: 0..639
    int tap = c >> 7;
    int rem = c & 127;
    int kt = rem >> 4, nt = rem & 15;

    float v0 = tapw[0], v1 = tapw[1], v2 = tapw[2], v3 = tapw[3], v4 = tapw[4];
    float mx = fmaxf(fmaxf(fmaxf(v0, v1), fmaxf(v2, v3)), v4);
    float e0 = expf(v0 - mx), e1 = expf(v1 - mx), e2 = expf(v2 - mx),
          e3 = expf(v3 - mx), e4 = expf(v4 - mx);
    float inv = 1.0f / (e0 + e1 + e2 + e3 + e4);
    float tws[5] = {e0 * inv, e1 * inv, e2 * inv, e3 * inv, e4 * inv};
    float tw = tws[tap];

    int kbase = 32 * kt + 8 * (l >> 4);
    int n = 16 * nt + (l & 15);
    const float* W = W_fb + tap * 65536;
    unsigned short t[8];
#pragma unroll
    for (int j = 0; j < 8; ++j) t[j] = f2bf(tw * W[(kbase + j) * 256 + n]);
    uint4 o;
    o.x = (unsigned)t[0] | ((unsigned)t[1] << 16);
    o.y = (unsigned)t[2] | ((unsigned)t[3] << 16);
    o.z = (unsigned)t[4] | ((unsigned)t[5] << 16);
    o.w = (unsigned)t[6] | ((unsigned)t[7] << 16);
    *(uint4*)(bp + (size_t)(c * 64 + l) * 8) = o;
}

// ---- Main kernel: one WG per batch, 8 waves; wave w owns s in [32w, 32w+32) ----
__global__ __launch_bounds__(NTHR, 1)
void reservoir_mfma(const float* __restrict__ x,
                    const float* __restrict__ W_in,
                    const float* __restrict__ bias,
                    const unsigned short* __restrict__ bp,
                    float* __restrict__ out)
{
    const int b    = blockIdx.x;
    const int tid  = threadIdx.x;
    const int lane = tid & 63;
    const int w    = tid >> 6;
    const int l15  = lane & 15;
    const int quad = lane >> 4;

    __shared__ float xs[TT];                             // 8 KB
    __shared__ unsigned short hwinb[8][2][HW_PAD];       // 8.25 KB: h ring, bf16 hi/lo
    __shared__ unsigned short hbcb[BLK][2][HB_PAD];      // 72.8 KB: far history hi/lo
    __shared__ float Gl[BLK][257];                       // 24.1 KB: far-tap results

    for (int i = tid; i < TT; i += NTHR) xs[i] = x[b * TT + i];
    {
        unsigned* hz = (unsigned*)&hwinb[0][0][0];
        for (int i = tid; i < 8 * 2 * HW_PAD / 2; i += NTHR) hz[i] = 0u;
    }

    // Resident B-fragments: tap d=1 (b1) and d=4 (b4). 128 VGPRs total.
    const bf16x8* bpv = (const bf16x8*)bp;
    bf16x8 b1[8][2], b4[8][2];
#pragma unroll
    for (int kt = 0; kt < 8; ++kt)
#pragma unroll
        for (int u = 0; u < 2; ++u) {
            int nt = 2 * w + u;
            b1[kt][u] = bpv[((0 * 8 + kt) * 16 + nt) * 64 + lane];
            b4[kt][u] = bpv[((1 * 8 + kt) * 16 + nt) * 64 + lane];
        }

    const int s0g = 32 * w + l15, s1g = s0g + 16;
    const float win0 = W_in[s0g], win1 = W_in[s1g];
    const float bi0 = bias[s0g], bi1 = bias[s1g];
    float hp0 = 0.0f, hp1 = 0.0f;

    const float* outr = out + (size_t)b * TT * RR;
    float*       outw = out + (size_t)b * TT * RR;

    __syncthreads();

    for (int t0 = 0; t0 < TT; t0 += BLK) {
        // ---- stage far history (pre-softmax-scaled W, so pure hi/lo cvt) ----
#pragma unroll 1
        for (int it = 0; it < 18; ++it) {                 // 18*512 = 9216 = 24*768/2
            int i = it * NTHR + tid;
            int j = i / 384;
            int p = i - j * 384;
            int r = 2 * p;
            int kf = r >> 8, rr = r & 255;
            int dk = (kf == 0) ? 24 : ((kf == 1) ? 96 : 168);
            int tt = t0 + j - dk;
            float vx = 0.0f, vy = 0.0f;
            if (tt >= 0) { float2 v = *(const float2*)(outr + tt * RR + rr); vx = v.x; vy = v.y; }
            unsigned short h0 = f2bf(vx), h1 = f2bf(vy);
            unsigned short q0 = f2bf(vx - bf2f(h0)), q1 = f2bf(vy - bf2f(h1));
            *(unsigned*)&hbcb[j][0][r] = (unsigned)h0 | ((unsigned)h1 << 16);
            *(unsigned*)&hbcb[j][1][r] = (unsigned)q0 | ((unsigned)q1 << 16);
        }
        __syncthreads();

        // ---- far GEMM: C[24 j][32 s/wave] over K=768, hi+lo A ----
        f32x4 zf = {0.f, 0.f, 0.f, 0.f};
        f32x4 cf00 = zf, cf01 = zf, cf10 = zf, cf11 = zf;
        const int r0a = l15;              // m-tile 0: j = 0..15
        const int r1a = 16 + (l15 & 7);   // m-tile 1: j = 16..23 (dup rows -> C rows 8..15 discarded)
#pragma unroll 1
        for (int ft = 0; ft < 24; ++ft) {
            int tap = 2 + (ft >> 3), ktp = ft & 7;
            bf16x8 B0 = bpv[((tap * 8 + ktp) * 16 + 2 * w + 0) * 64 + lane];
            bf16x8 B1 = bpv[((tap * 8 + ktp) * 16 + 2 * w + 1) * 64 + lane];
            int ro = 32 * ft + 8 * quad;
#pragma unroll
            for (int var = 0; var < 2; ++var) {
                bf16x8 a0 = *(const bf16x8*)&hbcb[r0a][var][ro];
                bf16x8 a1 = *(const bf16x8*)&hbcb[r1a][var][ro];
                cf00 = __builtin_amdgcn_mfma_f32_16x16x32_bf16(a0, B0, cf00, 0, 0, 0);
                cf01 = __builtin_amdgcn_mfma_f32_16x16x32_bf16(a0, B1, cf01, 0, 0, 0);
                cf10 = __builtin_amdgcn_mfma_f32_16x16x32_bf16(a1, B0, cf10, 0, 0, 0);
                cf11 = __builtin_amdgcn_mfma_f32_16x16x32_bf16(a1, B1, cf11, 0, 0, 0);
            }
        }
        // writeback: C row = quad*4 + i; j = 16*m0 + row
#pragma unroll
        for (int i = 0; i < 4; ++i) {
            int j0 = 4 * quad + i;
            Gl[j0][16 * (2 * w + 0) + l15] = cf00[i];
            Gl[j0][16 * (2 * w + 1) + l15] = cf01[i];
            int j1 = 16 + 4 * quad + i;
            if (j1 < BLK) {
                Gl[j1][16 * (2 * w + 0) + l15] = cf10[i];
                Gl[j1][16 * (2 * w + 1) + l15] = cf11[i];
            }
        }
        __syncthreads();

        // ---- sequential sub-blocks of 4 steps ----
        const int tend = (t0 + BLK < TT) ? (t0 + BLK) : TT;
#pragma unroll 1
        for (int t4 = t0; t4 < tend; t4 += 4) {
            // tap d=4: M=4 MFMA (A rows m map to steps t4+m via h(t4-4+m), m<4 valid)
            f32x4 c40 = zf, c41 = zf;
            const int sl = (t4 - 4 + (l15 & 3)) & 7;
#pragma unroll
            for (int kt = 0; kt < 8; ++kt) {
                int ro = 32 * kt + 8 * quad;
#pragma unroll
                for (int var = 0; var < 2; ++var) {
                    bf16x8 a = *(const bf16x8*)&hwinb[sl][var][ro];
                    c40 = __builtin_amdgcn_mfma_f32_16x16x32_bf16(a, b4[kt][0], c40, 0, 0, 0);
                    c41 = __builtin_amdgcn_mfma_f32_16x16x32_bf16(a, b4[kt][1], c41, 0, 0, 0);
                }
            }
            // 4 sequential steps; tap d=1 per step (M=1, broadcast A -> all C rows equal)
#pragma unroll
            for (int u = 0; u < 4; ++u) {
                const int t = t4 + u;
                const int sp = (t - 1) & 7;
                f32x4 c10 = zf, c11 = zf;
#pragma unroll
                for (int kt = 0; kt < 8; ++kt) {
                    int ro = 32 * kt + 8 * quad;
#pragma unroll
                    for (int var = 0; var < 2; ++var) {
                        bf16x8 a = *(const bf16x8*)&hwinb[sp][var][ro];
                        c10 = __builtin_amdgcn_mfma_f32_16x16x32_bf16(a, b1[kt][0], c10, 0, 0, 0);
                        c11 = __builtin_amdgcn_mfma_f32_16x16x32_bf16(a, b1[kt][1], c11, 0, 0, 0);
                    }
                }
                // update (valid on lanes 0..15: C row 0 -> component 0)
                float xv = xs[t];
                int jj = t - t0;
                float f0 = c10[0] + c40[u] + Gl[jj][s0g] + bi0 + xv * win0;
                float f1 = c11[0] + c41[u] + Gl[jj][s1g] + bi1 + xv * win1;
                float h0 = 0.9f * hp0 + 0.1f * tanhf(f0);
                float h1 = 0.9f * hp1 + 0.1f * tanhf(f1);
                hp0 = h0; hp1 = h1;
                const int wsl = t & 7;
                if (lane < 16) {
                    unsigned short hh0 = f2bf(h0), hh1 = f2bf(h1);
                    hwinb[wsl][0][s0g] = hh0;
                    hwinb[wsl][0][s1g] = hh1;
                    hwinb[wsl][1][s0g] = f2bf(h0 - bf2f(hh0));
                    hwinb[wsl][1][s1g] = f2bf(h1 - bf2f(hh1));
                    outw[t * RR + s0g] = h0;
                    outw[t * RR + s1g] = h1;
                }
                __syncthreads();
            }
        }
    }
}

extern "C" void kernel_launch(void* const* d_in, const int* in_sizes, int n_in,
                              void* d_out, int out_size, void* d_ws, size_t ws_size,
                              hipStream_t stream) {
    const float* x    = (const float*)d_in[0];   // (64, 2048, 1)
    const float* W_in = (const float*)d_in[1];   // (256, 1)
    const float* W_fb = (const float*)d_in[2];   // (5, 256, 256)
    const float* tapw = (const float*)d_in[3];   // (5,)
    const float* bias = (const float*)d_in[4];   // (256,)
    float* out = (float*)d_out;                  // (64, 2048, 256)
    unsigned short* bp = (unsigned short*)d_ws;  // 640 KB packed bf16 B-fragments

    pack_weights<<<160, 256, 0, stream>>>(W_fb, tapw, bp);
    reservoir_mfma<<<BB, NTHR, 0, stream>>>(x, W_in, bias, bp, out);
}